// Round 1
// baseline (1161.076 us; speedup 1.0000x reference)
//
#include <hip/hip_runtime.h>

// ---------------- problem constants ----------------
constexpr int D_   = 256;
constexpr int NH_  = 8;
constexpr int DH_  = 32;
constexpr int NL_  = 4;
constexpr int NP_  = 4;
constexpr int FF_  = 1024;
constexpr int B_   = 2;
constexpr int S_   = 16660;
constexpr int NR_  = B_ * S_;   // 33320 rows

// ---------------- elementwise add: q = src + pos ----------------
__global__ __launch_bounds__(256) void add_kernel(const float* __restrict__ a,
                                                  const float* __restrict__ b,
                                                  float* __restrict__ o, int n4) {
  int i = blockIdx.x * 256 + threadIdx.x;
  if (i >= n4) return;
  float4 av = ((const float4*)a)[i];
  float4 bv = ((const float4*)b)[i];
  float4 ov = {av.x + bv.x, av.y + bv.y, av.z + bv.z, av.w + bv.w};
  ((float4*)o)[i] = ov;
}

// ---------------- fp32 tiled GEMM: C[M,N] = A[M,K] @ W[K,N] + bias ----------------
// 128x128 tile, BK=16, 256 threads, 8x8 per thread (split 4+4 to avoid LDS conflicts)
template<bool RELU>
__global__ __launch_bounds__(256, 2)
void gemm128(const float* __restrict__ A, const float* __restrict__ W,
             const float* __restrict__ bias, float* __restrict__ C,
             int M, int N, int K) {
  __shared__ __align__(16) float As[16][132];   // [k][m], padded
  __shared__ __align__(16) float Ws[16][132];   // [k][n], padded
  const int tid = threadIdx.x;
  const int tx = tid & 15, ty = tid >> 4;
  const int brow = blockIdx.x * 128, bcol = blockIdx.y * 128;
  float acc[8][8] = {};

  for (int bk = 0; bk < K; bk += 16) {
    // A tile: 128 rows x 16 k  (512 float4 loads)
#pragma unroll
    for (int it = 0; it < 2; ++it) {
      int i = tid + it * 256;          // 0..511
      int r = i >> 2;                  // row in tile 0..127
      int kc = (i & 3) << 2;           // k offset 0,4,8,12
      float4 v = {0.f, 0.f, 0.f, 0.f};
      int row = brow + r;
      if (row < M) v = *(const float4*)(A + (size_t)row * K + bk + kc);
      As[kc + 0][r] = v.x; As[kc + 1][r] = v.y;
      As[kc + 2][r] = v.z; As[kc + 3][r] = v.w;
    }
    // W tile: 16 k-rows x 128 cols
#pragma unroll
    for (int it = 0; it < 2; ++it) {
      int i = tid + it * 256;
      int r = i >> 5;                  // 0..15
      int c = (i & 31) << 2;           // 0..124
      *(float4*)&Ws[r][c] = *(const float4*)(W + (size_t)(bk + r) * N + bcol + c);
    }
    __syncthreads();
#pragma unroll
    for (int kk = 0; kk < 16; ++kk) {
      float av[8], wv[8];
      *(float4*)&av[0] = *(const float4*)&As[kk][ty * 4];
      *(float4*)&av[4] = *(const float4*)&As[kk][64 + ty * 4];
      *(float4*)&wv[0] = *(const float4*)&Ws[kk][tx * 4];
      *(float4*)&wv[4] = *(const float4*)&Ws[kk][64 + tx * 4];
#pragma unroll
      for (int i = 0; i < 8; ++i)
#pragma unroll
        for (int j = 0; j < 8; ++j)
          acc[i][j] = fmaf(av[i], wv[j], acc[i][j]);
    }
    __syncthreads();
  }

  float bv[8];
  *(float4*)&bv[0] = *(const float4*)(bias + bcol + tx * 4);
  *(float4*)&bv[4] = *(const float4*)(bias + bcol + 64 + tx * 4);
#pragma unroll
  for (int i = 0; i < 8; ++i) {
    int row = brow + ((i < 4) ? (ty * 4 + i) : (64 + ty * 4 + (i - 4)));
    if (row >= M) continue;
    float o[8];
#pragma unroll
    for (int j = 0; j < 8; ++j) {
      o[j] = acc[i][j] + bv[j];
      if (RELU) o[j] = fmaxf(o[j], 0.0f);
    }
    *(float4*)(C + (size_t)row * N + bcol + tx * 4)      = *(float4*)&o[0];
    *(float4*)(C + (size_t)row * N + bcol + 64 + tx * 4) = *(float4*)&o[4];
  }
}

// ---------------- MSDA sampling ----------------
// block = 256 threads = 8 heads x 32 channels; one block per (b,s)
__global__ __launch_bounds__(256)
void msda_kernel(const float* __restrict__ value, const float* __restrict__ offs,
                 const float* __restrict__ attn, const float* __restrict__ ref,
                 float* __restrict__ out) {
  const int n = blockIdx.x;            // 0..NR-1  (n = b*S + s)
  const int b = n / S_;
  const int tid = threadIdx.x;
  const int h = tid >> 5;
  const int c = tid & 31;

  // softmax over 16 logits (redundant across the 32 channel lanes — cheap)
  float lg[16];
  const float* ap = attn + (size_t)n * 128 + h * 16;
  float m = -1e30f;
#pragma unroll
  for (int i = 0; i < 16; ++i) { lg[i] = ap[i]; m = fmaxf(m, lg[i]); }
  float ssum = 0.f;
#pragma unroll
  for (int i = 0; i < 16; ++i) { lg[i] = __expf(lg[i] - m); ssum += lg[i]; }
  const float rs = 1.0f / ssum;

  const float* op = offs + (size_t)n * 256 + h * 32;
  const int   Hs[4] = {112, 56, 28, 14};
  const int   Wsz[4] = {112, 56, 28, 14};
  const int   st[4] = {0, 12544, 15680, 16464};

  float acc = 0.f;
#pragma unroll
  for (int l = 0; l < 4; ++l) {
    const float refx = ref[((size_t)n * 4 + l) * 2 + 0];
    const float refy = ref[((size_t)n * 4 + l) * 2 + 1];
    const int Hl = Hs[l], Wl = Wsz[l];
    const float fW = (float)Wl, fH = (float)Hl;
    const float* vbase = value + ((size_t)b * S_ + st[l]) * 256 + h * 32 + c;
#pragma unroll
    for (int p = 0; p < 4; ++p) {
      float ox = op[(l * 4 + p) * 2 + 0];
      float oy = op[(l * 4 + p) * 2 + 1];
      float locx = refx + ox / fW;
      float locy = refy + oy / fH;
      float x = locx * fW - 0.5f;
      float y = locy * fH - 0.5f;
      float x0f = floorf(x), y0f = floorf(y);
      float dx = x - x0f, dy = y - y0f;
      int x0 = (int)x0f, y0 = (int)y0f;
      float sv = 0.f;
#pragma unroll
      for (int cy = 0; cy < 2; ++cy) {
        int yy = y0 + cy;
        bool vy = (yy >= 0) && (yy < Hl);
        int yc = min(max(yy, 0), Hl - 1);
        float wy = cy ? dy : (1.f - dy);
#pragma unroll
        for (int cx = 0; cx < 2; ++cx) {
          int xx = x0 + cx;
          bool vx = (xx >= 0) && (xx < Wl);
          int xc = min(max(xx, 0), Wl - 1);
          float wx = cx ? dx : (1.f - dx);
          float w = wx * wy * ((vx && vy) ? 1.f : 0.f);
          float v = vbase[(size_t)(yc * Wl + xc) * 256];
          sv = fmaf(w, v, sv);
        }
      }
      acc = fmaf(lg[l * 4 + p] * rs, sv, acc);
    }
  }
  out[(size_t)n * 256 + h * 32 + c] = acc;
}

// ---------------- residual add + LayerNorm (wave per row) ----------------
__global__ __launch_bounds__(256)
void add_ln_kernel(const float* __restrict__ a, const float* __restrict__ r,
                   const float* __restrict__ g, const float* __restrict__ be,
                   float* __restrict__ out, int M) {
  const int wave = threadIdx.x >> 6;
  const int lane = threadIdx.x & 63;
  const int row = blockIdx.x * 4 + wave;
  if (row >= M) return;
  const float4 av = *(const float4*)(a + (size_t)row * 256 + lane * 4);
  const float4 rv = *(const float4*)(r + (size_t)row * 256 + lane * 4);
  float4 v = {av.x + rv.x, av.y + rv.y, av.z + rv.z, av.w + rv.w};
  float s  = v.x + v.y + v.z + v.w;
  float s2 = v.x * v.x + v.y * v.y + v.z * v.z + v.w * v.w;
#pragma unroll
  for (int o = 32; o > 0; o >>= 1) {
    s  += __shfl_xor(s, o, 64);
    s2 += __shfl_xor(s2, o, 64);
  }
  const float mean = s * (1.f / 256.f);
  const float var  = s2 * (1.f / 256.f) - mean * mean;
  const float rstd = rsqrtf(var + 1e-5f);
  const float4 gv = *(const float4*)(g + lane * 4);
  const float4 bv = *(const float4*)(be + lane * 4);
  float4 o4;
  o4.x = (v.x - mean) * rstd * gv.x + bv.x;
  o4.y = (v.y - mean) * rstd * gv.y + bv.y;
  o4.z = (v.z - mean) * rstd * gv.z + bv.z;
  o4.w = (v.w - mean) * rstd * gv.w + bv.w;
  *(float4*)(out + (size_t)row * 256 + lane * 4) = o4;
}

// ---------------- launch ----------------
extern "C" void kernel_launch(void* const* d_in, const int* in_sizes, int n_in,
                              void* d_out, int out_size, void* d_ws, size_t ws_size,
                              hipStream_t stream) {
  const float* src    = (const float*)d_in[0];
  const float* pos    = (const float*)d_in[1];
  const float* refpts = (const float*)d_in[2];
  // d_in[3] spatial_shapes, d_in[4] level_start_index: compile-time constants
  const float* W_off  = (const float*)d_in[5];
  const float* b_off  = (const float*)d_in[6];
  const float* W_attn = (const float*)d_in[7];
  const float* b_attn = (const float*)d_in[8];
  const float* W_val  = (const float*)d_in[9];
  const float* b_val  = (const float*)d_in[10];
  const float* W_out  = (const float*)d_in[11];
  const float* b_out  = (const float*)d_in[12];
  const float* g1     = (const float*)d_in[13];
  const float* be1    = (const float*)d_in[14];
  const float* g2     = (const float*)d_in[15];
  const float* be2    = (const float*)d_in[16];
  const float* W1     = (const float*)d_in[17];
  const float* b1     = (const float*)d_in[18];
  const float* W2     = (const float*)d_in[19];
  const float* b2     = (const float*)d_in[20];
  float* out = (float*)d_out;
  float* ws  = (float*)d_ws;

  const size_t NF = (size_t)NR_ * 256;   // floats per [N,256] buffer
  float* q    = ws;             // later reused as x (LN1 output)
  float* msda = ws + NF;
  float* tmp  = ws + 2 * NF;
  float* valb = ws + 3 * NF;
  float* offs = ws + 4 * NF;
  float* attn = ws + 5 * NF;    // N*128 floats
  float* hid  = ws + 3 * NF;    // N*1024 floats; overlays valb/offs/attn (dead by then)

  const int n4 = NR_ * 64;      // float4 count of a [N,256] buffer
  dim3 blk(256);
  dim3 g256((NR_ + 127) / 128, 2);
  dim3 g128((NR_ + 127) / 128, 1);
  dim3 gFF ((NR_ + 127) / 128, 8);

  // 1. q = src + pos
  add_kernel<<<(n4 + 255) / 256, blk, 0, stream>>>(src, pos, q, n4);
  // 2. value = src @ W_val + b_val
  gemm128<false><<<g256, blk, 0, stream>>>(src, W_val, b_val, valb, NR_, 256, 256);
  // 3. offsets = q @ W_off + b_off
  gemm128<false><<<g256, blk, 0, stream>>>(q, W_off, b_off, offs, NR_, 256, 256);
  // 4. attn logits = q @ W_attn + b_attn
  gemm128<false><<<g128, blk, 0, stream>>>(q, W_attn, b_attn, attn, NR_, 128, 256);
  // 5. MSDA sampling (softmax fused)
  msda_kernel<<<NR_, blk, 0, stream>>>(valb, offs, attn, refpts, msda);
  // 6. out-proj
  gemm128<false><<<g256, blk, 0, stream>>>(msda, W_out, b_out, tmp, NR_, 256, 256);
  // 7. x = LN(src + tmp)
  add_ln_kernel<<<(NR_ + 3) / 4, blk, 0, stream>>>(tmp, src, g1, be1, q, NR_);
  // 8. hid = relu(x @ W1 + b1)
  gemm128<true><<<gFF, blk, 0, stream>>>(q, W1, b1, hid, NR_, 1024, 256);
  // 9. tmp = hid @ W2 + b2
  gemm128<false><<<g256, blk, 0, stream>>>(hid, W2, b2, tmp, NR_, 256, 1024);
  // 10. out = LN(x + tmp)
  add_ln_kernel<<<(NR_ + 3) / 4, blk, 0, stream>>>(tmp, q, g2, be2, out, NR_);
}

// Round 2
// 628.636 us; speedup vs baseline: 1.8470x; 1.8470x over previous
//
#include <hip/hip_runtime.h>

// ---------------- problem constants ----------------
constexpr int D_   = 256;
constexpr int NH_  = 8;
constexpr int DH_  = 32;
constexpr int NL_  = 4;
constexpr int NP_  = 4;
constexpr int FF_  = 1024;
constexpr int B_   = 2;
constexpr int S_   = 16660;
constexpr int NR_  = B_ * S_;   // 33320 rows

typedef __attribute__((ext_vector_type(8))) short bf16x8;
typedef __attribute__((ext_vector_type(4))) float f32x4;

__device__ __forceinline__ ushort f2bf(float f) {
  unsigned u = __float_as_uint(f);
  return (ushort)((u + 0x7FFFu + ((u >> 16) & 1u)) >> 16);
}
__device__ __forceinline__ float bf2f(ushort h) {
  return __uint_as_float(((unsigned)h) << 16);
}

// ---------------- prep: qb = bf16(src+pos), srcb = bf16(src) ----------------
__global__ __launch_bounds__(256)
void prep_kernel(const float* __restrict__ src, const float* __restrict__ pos,
                 ushort* __restrict__ qb, ushort* __restrict__ srcb, int n4) {
  int i = blockIdx.x * 256 + threadIdx.x;
  if (i >= n4) return;
  float4 s = ((const float4*)src)[i];
  float4 p = ((const float4*)pos)[i];
  ushort4 sb = {f2bf(s.x), f2bf(s.y), f2bf(s.z), f2bf(s.w)};
  ushort4 q  = {f2bf(s.x + p.x), f2bf(s.y + p.y), f2bf(s.z + p.z), f2bf(s.w + p.w)};
  ((ushort4*)srcb)[i] = sb;
  ((ushort4*)qb)[i]   = q;
}

// ---------------- weight convert + transpose: Wt[n][k] = bf16(W[k][n]) ----------------
__global__ __launch_bounds__(256)
void cvt_weights(const float* __restrict__ Woff, const float* __restrict__ Wattn,
                 const float* __restrict__ Wval, const float* __restrict__ Wout,
                 const float* __restrict__ W1,  const float* __restrict__ W2,
                 ushort* __restrict__ out) {
  const int wi = blockIdx.y;
  const int i = blockIdx.x * 256 + threadIdx.x;
  const float* src; int K, N; size_t off;
  switch (wi) {
    case 0: src = Woff;  K = 256;  N = 256;  off = 0;      break;
    case 1: src = Wattn; K = 256;  N = 128;  off = 65536;  break;
    case 2: src = Wval;  K = 256;  N = 256;  off = 98304;  break;
    case 3: src = Wout;  K = 256;  N = 256;  off = 163840; break;
    case 4: src = W1;    K = 256;  N = 1024; off = 229376; break;
    default:src = W2;    K = 1024; N = 256;  off = 491520; break;
  }
  if (i >= K * N) return;
  int k = i / N, n = i - k * N;
  out[off + (size_t)n * K + k] = f2bf(src[i]);
}

// ---------------- bf16 MFMA GEMM: C[M,N] = A[M,K] @ Wt[N,K]^T + bias ----------------
// 128x128 tile, BK=32, 256 thr (4 waves, 4x4 16x16x32 frags each),
// global_load_lds width-16 staging, k-granule XOR swizzle vs bank conflicts.
template<bool RELU, bool OUTBF16>
__global__ __launch_bounds__(256, 2)
void gemm_mfma(const ushort* __restrict__ A, const ushort* __restrict__ Wt,
               const float* __restrict__ bias, void* __restrict__ Cout,
               int M, int N, int K) {
  __shared__ ushort As[128 * 32];
  __shared__ ushort Bs[128 * 32];
  const int tid = threadIdx.x;
  const int l = tid & 63, w = tid >> 6;
  const int brow = blockIdx.x * 128, bcol = blockIdx.y * 128;

  // staging: wave w, chunk c in {0,1}: LDS ushort base = w*1024 + c*512, lane adds l*8
  // row-in-tile = w*32 + c*16 + (l>>2), kb_phys = l&3, kb_log = kb_phys ^ ((row>>1)&3)
  const int rA0 = w * 32 + (l >> 2);
  const int kbl = (l & 3) ^ ((rA0 >> 1) & 3);   // same for both chunks (+16 rows keeps (row>>1)&3)
  const ushort* agp0 = A  + (size_t)(brow + rA0)      * K + kbl * 8;
  const ushort* agp1 = A  + (size_t)(brow + rA0 + 16) * K + kbl * 8;
  const ushort* bgp0 = Wt + (size_t)(bcol + rA0)      * K + kbl * 8;
  const ushort* bgp1 = Wt + (size_t)(bcol + rA0 + 16) * K + kbl * 8;
  ushort* asl0 = As + w * 1024; ushort* asl1 = asl0 + 512;
  ushort* bsl0 = Bs + w * 1024; ushort* bsl1 = bsl0 + 512;

  // compute-phase lane constants
  const int l15 = l & 15;
  const int kg  = l >> 4;
  const int swz = (l15 >> 1) & 3;
  const int rbase = (w & 1) * 64, cbase = (w >> 1) * 64;
  const int aoff = (rbase + l15) * 32 + ((kg ^ swz) * 8);
  const int boff = (cbase + l15) * 32 + ((kg ^ swz) * 8);

  f32x4 acc[4][4];
#pragma unroll
  for (int i = 0; i < 4; ++i)
#pragma unroll
    for (int j = 0; j < 4; ++j) acc[i][j] = (f32x4){0.f, 0.f, 0.f, 0.f};

  for (int bk = 0; bk < K; bk += 32) {
    __builtin_amdgcn_global_load_lds(
        (const __attribute__((address_space(1))) void*)(agp0 + bk),
        (__attribute__((address_space(3))) void*)asl0, 16, 0, 0);
    __builtin_amdgcn_global_load_lds(
        (const __attribute__((address_space(1))) void*)(agp1 + bk),
        (__attribute__((address_space(3))) void*)asl1, 16, 0, 0);
    __builtin_amdgcn_global_load_lds(
        (const __attribute__((address_space(1))) void*)(bgp0 + bk),
        (__attribute__((address_space(3))) void*)bsl0, 16, 0, 0);
    __builtin_amdgcn_global_load_lds(
        (const __attribute__((address_space(1))) void*)(bgp1 + bk),
        (__attribute__((address_space(3))) void*)bsl1, 16, 0, 0);
    __syncthreads();

    bf16x8 af[4], bfr[4];
#pragma unroll
    for (int i = 0; i < 4; ++i) af[i]  = *(const bf16x8*)(As + aoff + i * 512);
#pragma unroll
    for (int j = 0; j < 4; ++j) bfr[j] = *(const bf16x8*)(Bs + boff + j * 512);
#pragma unroll
    for (int i = 0; i < 4; ++i)
#pragma unroll
      for (int j = 0; j < 4; ++j)
        acc[i][j] = __builtin_amdgcn_mfma_f32_16x16x32_bf16(af[i], bfr[j], acc[i][j], 0, 0, 0);
    __syncthreads();
  }

  // epilogue: D mapping col = lane&15, row = (lane>>4)*4 + r
  const int r0 = kg * 4;
#pragma unroll
  for (int j = 0; j < 4; ++j) {
    const int col = bcol + cbase + j * 16 + l15;
    const float bj = bias[col];
#pragma unroll
    for (int i = 0; i < 4; ++i) {
      const int rowb = brow + rbase + i * 16 + r0;
#pragma unroll
      for (int r = 0; r < 4; ++r) {
        const int row = rowb + r;
        if (row < M) {
          float v = acc[i][j][r] + bj;
          if (RELU) v = fmaxf(v, 0.f);
          if (OUTBF16) ((ushort*)Cout)[(size_t)row * N + col] = f2bf(v);
          else         ((float*)Cout)[(size_t)row * N + col]  = v;
        }
      }
    }
  }
}

// ---------------- MSDA sampling (bf16 value, bf16 out) ----------------
__global__ __launch_bounds__(256)
void msda_kernel(const ushort* __restrict__ value, const float* __restrict__ offs,
                 const float* __restrict__ attn, const float* __restrict__ ref,
                 ushort* __restrict__ out) {
  const int n = blockIdx.x;            // n = b*S + s
  const int b = n / S_;
  const int tid = threadIdx.x;
  const int h = tid >> 5;
  const int c = tid & 31;

  float lg[16];
  const float* ap = attn + (size_t)n * 128 + h * 16;
  float m = -1e30f;
#pragma unroll
  for (int i = 0; i < 16; ++i) { lg[i] = ap[i]; m = fmaxf(m, lg[i]); }
  float ssum = 0.f;
#pragma unroll
  for (int i = 0; i < 16; ++i) { lg[i] = __expf(lg[i] - m); ssum += lg[i]; }
  const float rs = 1.0f / ssum;

  const float* op = offs + (size_t)n * 256 + h * 32;
  const int Hs[4] = {112, 56, 28, 14};
  const int st[4] = {0, 12544, 15680, 16464};

  float acc = 0.f;
#pragma unroll
  for (int l = 0; l < 4; ++l) {
    const float refx = ref[((size_t)n * 4 + l) * 2 + 0];
    const float refy = ref[((size_t)n * 4 + l) * 2 + 1];
    const int Hl = Hs[l], Wl = Hs[l];
    const float fW = (float)Wl, fH = (float)Hl;
    const ushort* vbase = value + ((size_t)b * S_ + st[l]) * 256 + h * 32 + c;
#pragma unroll
    for (int p = 0; p < 4; ++p) {
      float ox = op[(l * 4 + p) * 2 + 0];
      float oy = op[(l * 4 + p) * 2 + 1];
      float x = (refx + ox / fW) * fW - 0.5f;
      float y = (refy + oy / fH) * fH - 0.5f;
      float x0f = floorf(x), y0f = floorf(y);
      float dx = x - x0f, dy = y - y0f;
      int x0 = (int)x0f, y0 = (int)y0f;
      float sv = 0.f;
#pragma unroll
      for (int cy = 0; cy < 2; ++cy) {
        int yy = y0 + cy;
        bool vy = (yy >= 0) && (yy < Hl);
        int yc = min(max(yy, 0), Hl - 1);
        float wy = cy ? dy : (1.f - dy);
#pragma unroll
        for (int cx = 0; cx < 2; ++cx) {
          int xx = x0 + cx;
          bool vx = (xx >= 0) && (xx < Wl);
          int xc = min(max(xx, 0), Wl - 1);
          float wx = cx ? dx : (1.f - dx);
          float wgt = wx * wy * ((vx && vy) ? 1.f : 0.f);
          float v = bf2f(vbase[(size_t)(yc * Wl + xc) * 256]);
          sv = fmaf(wgt, v, sv);
        }
      }
      acc = fmaf(lg[l * 4 + p] * rs, sv, acc);
    }
  }
  out[(size_t)n * 256 + h * 32 + c] = f2bf(acc);
}

// ---------------- residual add + LayerNorm (wave per row) ----------------
template<bool WB>
__global__ __launch_bounds__(256)
void add_ln_kernel(const float* __restrict__ a, const float* __restrict__ r,
                   const float* __restrict__ g, const float* __restrict__ be,
                   float* __restrict__ out, ushort* __restrict__ outb, int M) {
  const int wave = threadIdx.x >> 6;
  const int lane = threadIdx.x & 63;
  const int row = blockIdx.x * 4 + wave;
  if (row >= M) return;
  const float4 av = *(const float4*)(a + (size_t)row * 256 + lane * 4);
  const float4 rv = *(const float4*)(r + (size_t)row * 256 + lane * 4);
  float4 v = {av.x + rv.x, av.y + rv.y, av.z + rv.z, av.w + rv.w};
  float s  = v.x + v.y + v.z + v.w;
  float s2 = v.x * v.x + v.y * v.y + v.z * v.z + v.w * v.w;
#pragma unroll
  for (int o = 32; o > 0; o >>= 1) {
    s  += __shfl_xor(s, o, 64);
    s2 += __shfl_xor(s2, o, 64);
  }
  const float mean = s * (1.f / 256.f);
  const float var  = s2 * (1.f / 256.f) - mean * mean;
  const float rstd = rsqrtf(var + 1e-5f);
  const float4 gv = *(const float4*)(g + lane * 4);
  const float4 bv = *(const float4*)(be + lane * 4);
  float4 o4;
  o4.x = (v.x - mean) * rstd * gv.x + bv.x;
  o4.y = (v.y - mean) * rstd * gv.y + bv.y;
  o4.z = (v.z - mean) * rstd * gv.z + bv.z;
  o4.w = (v.w - mean) * rstd * gv.w + bv.w;
  *(float4*)(out + (size_t)row * 256 + lane * 4) = o4;
  if (WB) {
    ushort4 ob = {f2bf(o4.x), f2bf(o4.y), f2bf(o4.z), f2bf(o4.w)};
    ((ushort4*)(outb + (size_t)row * 256))[lane] = ob;
  }
}

// ---------------- launch ----------------
extern "C" void kernel_launch(void* const* d_in, const int* in_sizes, int n_in,
                              void* d_out, int out_size, void* d_ws, size_t ws_size,
                              hipStream_t stream) {
  const float* src    = (const float*)d_in[0];
  const float* pos    = (const float*)d_in[1];
  const float* refpts = (const float*)d_in[2];
  const float* W_off  = (const float*)d_in[5];
  const float* b_off  = (const float*)d_in[6];
  const float* W_attn = (const float*)d_in[7];
  const float* b_attn = (const float*)d_in[8];
  const float* W_val  = (const float*)d_in[9];
  const float* b_val  = (const float*)d_in[10];
  const float* W_out  = (const float*)d_in[11];
  const float* b_out  = (const float*)d_in[12];
  const float* g1     = (const float*)d_in[13];
  const float* be1    = (const float*)d_in[14];
  const float* g2     = (const float*)d_in[15];
  const float* be2    = (const float*)d_in[16];
  const float* W1     = (const float*)d_in[17];
  const float* b1     = (const float*)d_in[18];
  const float* W2     = (const float*)d_in[19];
  const float* b2     = (const float*)d_in[20];
  float* out = (float*)d_out;

  const size_t NF = (size_t)NR_ * 256;
  char* p = (char*)d_ws;
  ushort* qb   = (ushort*)p; p += NF * 2;   // xb overlays qb
  ushort* srcb = (ushort*)p; p += NF * 2;   // msdab overlays srcb
  ushort* valb = (ushort*)p; p += NF * 2;   // hid overlays valb..attn (NF*8 bytes)
  float*  offs = (float*) p; p += NF * 4;
  float*  attn = (float*) p; p += NF * 2;   // [N,128] fp32
  float*  tmp  = (float*) p; p += NF * 4;
  float*  x    = (float*) p; p += NF * 4;
  ushort* Wt   = (ushort*)p; p += 753664 * 2;
  ushort* msdab = srcb;
  ushort* xb    = qb;
  ushort* hid   = valb;
  ushort* WtOff  = Wt;
  ushort* WtAttn = Wt + 65536;
  ushort* WtVal  = Wt + 98304;
  ushort* WtOut  = Wt + 163840;
  ushort* Wt1    = Wt + 229376;
  ushort* Wt2    = Wt + 491520;

  dim3 blk(256);
  const int n4 = NR_ * 64;
  const int gr = (NR_ + 127) / 128;   // 261

  prep_kernel<<<(n4 + 255) / 256, blk, 0, stream>>>(src, pos, qb, srcb, n4);
  cvt_weights<<<dim3(1024, 6), blk, 0, stream>>>(W_off, W_attn, W_val, W_out, W1, W2, Wt);
  // value = src @ W_val + b_val  (bf16 out for cheap gathers)
  gemm_mfma<false, true ><<<dim3(gr, 2), blk, 0, stream>>>(srcb, WtVal, b_val, valb, NR_, 256, 256);
  // offsets / attn logits
  gemm_mfma<false, false><<<dim3(gr, 2), blk, 0, stream>>>(qb, WtOff, b_off, offs, NR_, 256, 256);
  gemm_mfma<false, false><<<dim3(gr, 1), blk, 0, stream>>>(qb, WtAttn, b_attn, attn, NR_, 128, 256);
  // sampling
  msda_kernel<<<NR_, blk, 0, stream>>>(valb, offs, attn, refpts, msdab);
  // out-proj
  gemm_mfma<false, false><<<dim3(gr, 2), blk, 0, stream>>>(msdab, WtOut, b_out, tmp, NR_, 256, 256);
  // x = LN(src + tmp), bf16 copy for FFN
  add_ln_kernel<true ><<<(NR_ + 3) / 4, blk, 0, stream>>>(tmp, src, g1, be1, x, xb, NR_);
  // FFN
  gemm_mfma<true,  true ><<<dim3(gr, 8), blk, 0, stream>>>(xb, Wt1, b1, hid, NR_, 1024, 256);
  gemm_mfma<false, false><<<dim3(gr, 2), blk, 0, stream>>>(hid, Wt2, b2, tmp, NR_, 256, 1024);
  // out = LN(x + tmp)
  add_ln_kernel<false><<<(NR_ + 3) / 4, blk, 0, stream>>>(tmp, x, g2, be2, out, nullptr, NR_);
}

// Round 5
// 442.400 us; speedup vs baseline: 2.6245x; 1.4210x over previous
//
#include <hip/hip_runtime.h>

// ---------------- problem constants ----------------
constexpr int D_   = 256;
constexpr int NH_  = 8;
constexpr int DH_  = 32;
constexpr int NL_  = 4;
constexpr int NP_  = 4;
constexpr int FF_  = 1024;
constexpr int B_   = 2;
constexpr int S_   = 16660;
constexpr int NR_  = B_ * S_;   // 33320 rows

typedef __attribute__((ext_vector_type(8))) short bf16x8;
typedef __attribute__((ext_vector_type(4))) float f32x4;

__device__ __forceinline__ ushort f2bf(float f) {
  unsigned u = __float_as_uint(f);
  return (ushort)((u + 0x7FFFu + ((u >> 16) & 1u)) >> 16);
}

// ---------------- prep: qb = bf16(src+pos), srcb = bf16(src) ----------------
__global__ __launch_bounds__(256)
void prep_kernel(const float* __restrict__ src, const float* __restrict__ pos,
                 ushort* __restrict__ qb, ushort* __restrict__ srcb, int n4) {
  int i = blockIdx.x * 256 + threadIdx.x;
  if (i >= n4) return;
  float4 s = ((const float4*)src)[i];
  float4 p = ((const float4*)pos)[i];
  ushort4 sb = {f2bf(s.x), f2bf(s.y), f2bf(s.z), f2bf(s.w)};
  ushort4 q  = {f2bf(s.x + p.x), f2bf(s.y + p.y), f2bf(s.z + p.z), f2bf(s.w + p.w)};
  ((ushort4*)srcb)[i] = sb;
  ((ushort4*)qb)[i]   = q;
}

// ---------------- weight convert + transpose: Wt[n][k] = bf16(W[k][n]) ----------------
__global__ __launch_bounds__(256)
void cvt_weights(const float* __restrict__ Woff, const float* __restrict__ Wattn,
                 const float* __restrict__ Wval, const float* __restrict__ Wout,
                 const float* __restrict__ W1,  const float* __restrict__ W2,
                 ushort* __restrict__ out) {
  const int wi = blockIdx.y;
  const int i = blockIdx.x * 256 + threadIdx.x;
  const float* src; int K, N; size_t off;
  switch (wi) {
    case 0: src = Woff;  K = 256;  N = 256;  off = 0;      break;
    case 1: src = Wattn; K = 256;  N = 128;  off = 65536;  break;
    case 2: src = Wval;  K = 256;  N = 256;  off = 98304;  break;
    case 3: src = Wout;  K = 256;  N = 256;  off = 163840; break;
    case 4: src = W1;    K = 256;  N = 1024; off = 229376; break;
    default:src = W2;    K = 1024; N = 256;  off = 491520; break;
  }
  if (i >= K * N) return;
  int k = i / N, n = i - k * N;
  out[off + (size_t)n * K + k] = f2bf(src[i]);
}

// ---------------- bf16 MFMA GEMM: C[M,N] = A[M,K] @ Wt[N,K]^T + bias ----------------
template<bool RELU, bool OUTBF16>
__global__ __launch_bounds__(256, 2)
void gemm_mfma(const ushort* __restrict__ A, const ushort* __restrict__ Wt,
               const float* __restrict__ bias, void* __restrict__ Cout,
               int M, int N, int K) {
  __shared__ ushort As[128 * 32];
  __shared__ ushort Bs[128 * 32];
  const int tid = threadIdx.x;
  const int l = tid & 63, w = tid >> 6;
  const int brow = blockIdx.x * 128, bcol = blockIdx.y * 128;

  const int rA0 = w * 32 + (l >> 2);
  const int kbl = (l & 3) ^ ((rA0 >> 1) & 3);
  const ushort* agp0 = A  + (size_t)(brow + rA0)      * K + kbl * 8;
  const ushort* agp1 = A  + (size_t)(brow + rA0 + 16) * K + kbl * 8;
  const ushort* bgp0 = Wt + (size_t)(bcol + rA0)      * K + kbl * 8;
  const ushort* bgp1 = Wt + (size_t)(bcol + rA0 + 16) * K + kbl * 8;
  ushort* asl0 = As + w * 1024; ushort* asl1 = asl0 + 512;
  ushort* bsl0 = Bs + w * 1024; ushort* bsl1 = bsl0 + 512;

  const int l15 = l & 15;
  const int kg  = l >> 4;
  const int swz = (l15 >> 1) & 3;
  const int rbase = (w & 1) * 64, cbase = (w >> 1) * 64;
  const int aoff = (rbase + l15) * 32 + ((kg ^ swz) * 8);
  const int boff = (cbase + l15) * 32 + ((kg ^ swz) * 8);

  f32x4 acc[4][4];
#pragma unroll
  for (int i = 0; i < 4; ++i)
#pragma unroll
    for (int j = 0; j < 4; ++j) acc[i][j] = (f32x4){0.f, 0.f, 0.f, 0.f};

  for (int bk = 0; bk < K; bk += 32) {
    __builtin_amdgcn_global_load_lds(
        (const __attribute__((address_space(1))) void*)(agp0 + bk),
        (__attribute__((address_space(3))) void*)asl0, 16, 0, 0);
    __builtin_amdgcn_global_load_lds(
        (const __attribute__((address_space(1))) void*)(agp1 + bk),
        (__attribute__((address_space(3))) void*)asl1, 16, 0, 0);
    __builtin_amdgcn_global_load_lds(
        (const __attribute__((address_space(1))) void*)(bgp0 + bk),
        (__attribute__((address_space(3))) void*)bsl0, 16, 0, 0);
    __builtin_amdgcn_global_load_lds(
        (const __attribute__((address_space(1))) void*)(bgp1 + bk),
        (__attribute__((address_space(3))) void*)bsl1, 16, 0, 0);
    __syncthreads();

    bf16x8 af[4], bfr[4];
#pragma unroll
    for (int i = 0; i < 4; ++i) af[i]  = *(const bf16x8*)(As + aoff + i * 512);
#pragma unroll
    for (int j = 0; j < 4; ++j) bfr[j] = *(const bf16x8*)(Bs + boff + j * 512);
#pragma unroll
    for (int i = 0; i < 4; ++i)
#pragma unroll
      for (int j = 0; j < 4; ++j)
        acc[i][j] = __builtin_amdgcn_mfma_f32_16x16x32_bf16(af[i], bfr[j], acc[i][j], 0, 0, 0);
    __syncthreads();
  }

  const int r0 = kg * 4;
#pragma unroll
  for (int j = 0; j < 4; ++j) {
    const int col = bcol + cbase + j * 16 + l15;
    const float bj = bias[col];
#pragma unroll
    for (int i = 0; i < 4; ++i) {
      const int rowb = brow + rbase + i * 16 + r0;
#pragma unroll
      for (int r = 0; r < 4; ++r) {
        const int row = rowb + r;
        if (row < M) {
          float v = acc[i][j][r] + bj;
          if (RELU) v = fmaxf(v, 0.f);
          if (OUTBF16) ((ushort*)Cout)[(size_t)row * N + col] = f2bf(v);
          else         ((float*)Cout)[(size_t)row * N + col]  = v;
        }
      }
    }
  }
}

// ---------------- MSDA sampling, descriptor-split ----------------
// Block = 256 threads = 4 queries. Phase 1: 512 descriptors (one per q,h,l,p):
// softmax + bilinear indices/weights computed ONCE, stored in LDS.
// Phase 2: wave per query, 8 lanes per head, ushort4 (4ch) gathers.
__global__ __launch_bounds__(256)
void msda_kernel(const ushort* __restrict__ value, const float* __restrict__ offs,
                 const float* __restrict__ attn, const float* __restrict__ ref,
                 ushort* __restrict__ out) {
  __shared__ int4   descI[4 * 136];   // q*136 + h*17 + lp  (pad 17 vs bank conflicts)
  __shared__ float4 descW[4 * 136];
  const int t = threadIdx.x;
  const int n0 = blockIdx.x * 4;

  const int Hs[4] = {112, 56, 28, 14};
  const int st[4] = {0, 12544, 15680, 16464};

  // ---- phase 1: 2 descriptors per thread ----
#pragma unroll
  for (int rep = 0; rep < 2; ++rep) {
    const int di = t + rep * 256;
    const int q = di >> 7, h = (di >> 4) & 7, lp = di & 15;
    const int lv = lp >> 2;
    const int n = n0 + q;

    // softmax over the 16 lanes sharing (q,h)
    float lg = attn[(size_t)n * 128 + h * 16 + lp];
    float mx = lg;
#pragma unroll
    for (int o = 8; o; o >>= 1) mx = fmaxf(mx, __shfl_xor(mx, o, 64));
    float e = __expf(lg - mx);
    float ssum = e;
#pragma unroll
    for (int o = 8; o; o >>= 1) ssum += __shfl_xor(ssum, o, 64);
    const float aw = e / ssum;

    const int Hl = Hs[lv], Wl = Hs[lv];
    const float fS = (float)Wl;
    const float refx = ref[((size_t)n * 4 + lv) * 2 + 0];
    const float refy = ref[((size_t)n * 4 + lv) * 2 + 1];
    const float ox = offs[(size_t)n * 256 + h * 32 + lp * 2 + 0];
    const float oy = offs[(size_t)n * 256 + h * 32 + lp * 2 + 1];
    // (refx + ox/W)*W - 0.5 == refx*W + ox - 0.5
    float x = fmaf(refx, fS, ox) - 0.5f;
    float y = fmaf(refy, fS, oy) - 0.5f;
    float x0f = floorf(x), y0f = floorf(y);
    float dx = x - x0f, dy = y - y0f;
    int x0 = (int)x0f, y0 = (int)y0f;
    int x0c = min(max(x0, 0), Wl - 1), x1c = min(max(x0 + 1, 0), Wl - 1);
    int y0c = min(max(y0, 0), Hl - 1), y1c = min(max(y0 + 1, 0), Hl - 1);
    bool vx0 = (x0 >= 0) && (x0 < Wl), vx1 = (x0 + 1 >= 0) && (x0 + 1 < Wl);
    bool vy0 = (y0 >= 0) && (y0 < Hl), vy1 = (y0 + 1 >= 0) && (y0 + 1 < Hl);
    int4 I;
    I.x = st[lv] + y0c * Wl + x0c;
    I.y = st[lv] + y0c * Wl + x1c;
    I.z = st[lv] + y1c * Wl + x0c;
    I.w = st[lv] + y1c * Wl + x1c;
    float4 Wv;
    Wv.x = (1.f - dx) * (1.f - dy) * ((vx0 && vy0) ? aw : 0.f);
    Wv.y = dx * (1.f - dy)         * ((vx1 && vy0) ? aw : 0.f);
    Wv.z = (1.f - dx) * dy         * ((vx0 && vy1) ? aw : 0.f);
    Wv.w = dx * dy                 * ((vx1 && vy1) ? aw : 0.f);
    const int slot = q * 136 + h * 17 + lp;
    descI[slot] = I;
    descW[slot] = Wv;
  }
  __syncthreads();

  // ---- phase 2: wave per query, 8 lanes per head, 4 channels per lane ----
  const int q = t >> 6, lane = t & 63;
  const int h = lane >> 3, c = lane & 7;
  const int n = n0 + q;
  const int b = n / S_;
  const ushort* base = value + (size_t)b * S_ * 256 + h * 32 + c * 4;

  float a0 = 0.f, a1 = 0.f, a2 = 0.f, a3 = 0.f;
#pragma unroll
  for (int pt = 0; pt < 16; ++pt) {
    const int slot = q * 136 + h * 17 + pt;
    int4 I = descI[slot];
    float4 Wv = descW[slot];
    int   Ia[4] = {I.x, I.y, I.z, I.w};
    float Wa[4] = {Wv.x, Wv.y, Wv.z, Wv.w};
#pragma unroll
    for (int cr = 0; cr < 4; ++cr) {
      uint2 u = *(const uint2*)(base + (size_t)Ia[cr] * 256);
      float f0 = __uint_as_float(u.x << 16);
      float f1 = __uint_as_float(u.x & 0xffff0000u);
      float f2 = __uint_as_float(u.y << 16);
      float f3 = __uint_as_float(u.y & 0xffff0000u);
      a0 = fmaf(Wa[cr], f0, a0);
      a1 = fmaf(Wa[cr], f1, a1);
      a2 = fmaf(Wa[cr], f2, a2);
      a3 = fmaf(Wa[cr], f3, a3);
    }
  }
  ushort4 o = {f2bf(a0), f2bf(a1), f2bf(a2), f2bf(a3)};
  *(ushort4*)(out + (size_t)n * 256 + h * 32 + c * 4) = o;
}

// ---------------- residual add + LayerNorm (wave per row) ----------------
template<bool WB>
__global__ __launch_bounds__(256)
void add_ln_kernel(const float* __restrict__ a, const float* __restrict__ r,
                   const float* __restrict__ g, const float* __restrict__ be,
                   float* __restrict__ out, ushort* __restrict__ outb, int M) {
  const int wave = threadIdx.x >> 6;
  const int lane = threadIdx.x & 63;
  const int row = blockIdx.x * 4 + wave;
  if (row >= M) return;
  const float4 av = *(const float4*)(a + (size_t)row * 256 + lane * 4);
  const float4 rv = *(const float4*)(r + (size_t)row * 256 + lane * 4);
  float4 v = {av.x + rv.x, av.y + rv.y, av.z + rv.z, av.w + rv.w};
  float s  = v.x + v.y + v.z + v.w;
  float s2 = v.x * v.x + v.y * v.y + v.z * v.z + v.w * v.w;
#pragma unroll
  for (int o = 32; o > 0; o >>= 1) {
    s  += __shfl_xor(s, o, 64);
    s2 += __shfl_xor(s2, o, 64);
  }
  const float mean = s * (1.f / 256.f);
  const float var  = s2 * (1.f / 256.f) - mean * mean;
  const float rstd = rsqrtf(var + 1e-5f);
  const float4 gv = *(const float4*)(g + lane * 4);
  const float4 bv = *(const float4*)(be + lane * 4);
  float4 o4;
  o4.x = (v.x - mean) * rstd * gv.x + bv.x;
  o4.y = (v.y - mean) * rstd * gv.y + bv.y;
  o4.z = (v.z - mean) * rstd * gv.z + bv.z;
  o4.w = (v.w - mean) * rstd * gv.w + bv.w;
  *(float4*)(out + (size_t)row * 256 + lane * 4) = o4;
  if (WB) {
    ushort4 ob = {f2bf(o4.x), f2bf(o4.y), f2bf(o4.z), f2bf(o4.w)};
    ((ushort4*)(outb + (size_t)row * 256))[lane] = ob;
  }
}

// ---------------- launch ----------------
extern "C" void kernel_launch(void* const* d_in, const int* in_sizes, int n_in,
                              void* d_out, int out_size, void* d_ws, size_t ws_size,
                              hipStream_t stream) {
  const float* src    = (const float*)d_in[0];
  const float* pos    = (const float*)d_in[1];
  const float* refpts = (const float*)d_in[2];
  const float* W_off  = (const float*)d_in[5];
  const float* b_off  = (const float*)d_in[6];
  const float* W_attn = (const float*)d_in[7];
  const float* b_attn = (const float*)d_in[8];
  const float* W_val  = (const float*)d_in[9];
  const float* b_val  = (const float*)d_in[10];
  const float* W_out  = (const float*)d_in[11];
  const float* b_out  = (const float*)d_in[12];
  const float* g1     = (const float*)d_in[13];
  const float* be1    = (const float*)d_in[14];
  const float* g2     = (const float*)d_in[15];
  const float* be2    = (const float*)d_in[16];
  const float* W1     = (const float*)d_in[17];
  const float* b1     = (const float*)d_in[18];
  const float* W2     = (const float*)d_in[19];
  const float* b2     = (const float*)d_in[20];
  float* out = (float*)d_out;

  const size_t NF = (size_t)NR_ * 256;
  char* p = (char*)d_ws;
  ushort* qb   = (ushort*)p; p += NF * 2;   // xb overlays qb
  ushort* srcb = (ushort*)p; p += NF * 2;   // msdab overlays srcb
  ushort* valb = (ushort*)p; p += NF * 2;   // hid overlays valb..attn
  float*  offs = (float*) p; p += NF * 4;
  float*  attn = (float*) p; p += NF * 2;   // [N,128] fp32
  float*  tmp  = (float*) p; p += NF * 4;
  float*  x    = (float*) p; p += NF * 4;
  ushort* Wt   = (ushort*)p; p += 753664 * 2;
  ushort* msdab = srcb;
  ushort* xb    = qb;
  ushort* hid   = valb;
  ushort* WtOff  = Wt;
  ushort* WtAttn = Wt + 65536;
  ushort* WtVal  = Wt + 98304;
  ushort* WtOut  = Wt + 163840;
  ushort* Wt1    = Wt + 229376;
  ushort* Wt2    = Wt + 491520;

  dim3 blk(256);
  const int n4 = NR_ * 64;
  const int gr = (NR_ + 127) / 128;   // 261

  prep_kernel<<<(n4 + 255) / 256, blk, 0, stream>>>(src, pos, qb, srcb, n4);
  cvt_weights<<<dim3(1024, 6), blk, 0, stream>>>(W_off, W_attn, W_val, W_out, W1, W2, Wt);
  gemm_mfma<false, true ><<<dim3(gr, 2), blk, 0, stream>>>(srcb, WtVal, b_val, valb, NR_, 256, 256);
  gemm_mfma<false, false><<<dim3(gr, 2), blk, 0, stream>>>(qb, WtOff, b_off, offs, NR_, 256, 256);
  gemm_mfma<false, false><<<dim3(gr, 1), blk, 0, stream>>>(qb, WtAttn, b_attn, attn, NR_, 128, 256);
  msda_kernel<<<NR_ / 4, blk, 0, stream>>>(valb, offs, attn, refpts, msdab);
  gemm_mfma<false, false><<<dim3(gr, 2), blk, 0, stream>>>(msdab, WtOut, b_out, tmp, NR_, 256, 256);
  add_ln_kernel<true ><<<(NR_ + 3) / 4, blk, 0, stream>>>(tmp, src, g1, be1, x, xb, NR_);
  gemm_mfma<true,  true ><<<dim3(gr, 8), blk, 0, stream>>>(xb, Wt1, b1, hid, NR_, 1024, 256);
  gemm_mfma<false, false><<<dim3(gr, 2), blk, 0, stream>>>(hid, Wt2, b2, tmp, NR_, 256, 1024);
  add_ln_kernel<false><<<(NR_ + 3) / 4, blk, 0, stream>>>(tmp, x, g2, be2, out, nullptr, NR_);
}

// Round 8
// 410.629 us; speedup vs baseline: 2.8276x; 1.0774x over previous
//
#include <hip/hip_runtime.h>

// ---------------- problem constants ----------------
constexpr int D_   = 256;
constexpr int NH_  = 8;
constexpr int DH_  = 32;
constexpr int NL_  = 4;
constexpr int NP_  = 4;
constexpr int FF_  = 1024;
constexpr int B_   = 2;
constexpr int S_   = 16660;
constexpr int NR_  = B_ * S_;   // 33320 rows

typedef __attribute__((ext_vector_type(8))) short bf16x8;
typedef __attribute__((ext_vector_type(4))) float f32x4;

__device__ __forceinline__ ushort f2bf(float f) {
  unsigned u = __float_as_uint(f);
  return (ushort)((u + 0x7FFFu + ((u >> 16) & 1u)) >> 16);
}

// ---------------- prep: qb = bf16(src+pos), srcb = bf16(src) ----------------
__global__ __launch_bounds__(256)
void prep_kernel(const float* __restrict__ src, const float* __restrict__ pos,
                 ushort* __restrict__ qb, ushort* __restrict__ srcb, int n4) {
  int i = blockIdx.x * 256 + threadIdx.x;
  if (i >= n4) return;
  float4 s = ((const float4*)src)[i];
  float4 p = ((const float4*)pos)[i];
  ushort4 sb = {f2bf(s.x), f2bf(s.y), f2bf(s.z), f2bf(s.w)};
  ushort4 q  = {f2bf(s.x + p.x), f2bf(s.y + p.y), f2bf(s.z + p.z), f2bf(s.w + p.w)};
  ((ushort4*)srcb)[i] = sb;
  ((ushort4*)qb)[i]   = q;
}

// ---------------- weight convert + transpose: Wt[n][k] = bf16(W[k][n]) ----------------
// layout (ushort offsets): Val 0 | OA(off 256 cols + attn 128 cols) 65536 | Out 163840
//                          | W1 229376 | W2 491520  (total 753664)
__global__ __launch_bounds__(256)
void cvt_weights(const float* __restrict__ Woff, const float* __restrict__ Wattn,
                 const float* __restrict__ Wval, const float* __restrict__ Wout,
                 const float* __restrict__ W1,  const float* __restrict__ W2,
                 ushort* __restrict__ out) {
  const int wi = blockIdx.y;
  const int i = blockIdx.x * 256 + threadIdx.x;
  const float* src; int K, N; size_t off;
  switch (wi) {
    case 0: src = Wval;  K = 256;  N = 256;  off = 0;      break;
    case 1: src = Woff;  K = 256;  N = 256;  off = 65536;  break;
    case 2: src = Wattn; K = 256;  N = 128;  off = 131072; break;
    case 3: src = Wout;  K = 256;  N = 256;  off = 163840; break;
    case 4: src = W1;    K = 256;  N = 1024; off = 229376; break;
    default:src = W2;    K = 1024; N = 256;  off = 491520; break;
  }
  if (i >= K * N) return;
  int k = i / N, n = i - k * N;
  out[off + (size_t)n * K + k] = f2bf(src[i]);
}

// ---------------- B-in-LDS GEMM for K=256: C[M,N] = A[M,256] @ Wpan^T + bias --------
// Block: 128 rows (x) x 128 cols (y). Whole 128x256 weight panel (64 KB) staged in LDS
// ONCE (swizzled-source global_load_lds, linear dest), ONE barrier, then each wave
// computes 2x 16-row slices with A-fragments loaded global->regs. No K-loop barriers.
// MODE: 0 = f32 out, 1 = bf16 out, 2 = bf16+relu out, 3 = split offs(f32)/attn(f32)
template<int MODE>
__global__ __launch_bounds__(256, 2)
void gemm_blds(const ushort* __restrict__ A, const ushort* __restrict__ Wpan,
               const float* __restrict__ bias, const float* __restrict__ bias2,
               void* __restrict__ C, void* __restrict__ C2, int M, int Ns) {
  __shared__ ushort Bs[128 * 256];   // 64 KB, [col][k] with k-granule XOR swizzle
  const int tid = threadIdx.x;
  const int l = tid & 63, w = tid >> 6;
  const int l15 = l & 15, kg = l >> 4;
  const int cxor = l15 & 7;
  const int bx = blockIdx.x, by = blockIdx.y;

  // ---- A fragments: 2 slices per wave (rows bx*128 + w*16 + l15, +64) ----
  const int r0 = bx * 128 + w * 16 + l15;
  const int r1 = r0 + 64;
  const int r0c = min(r0, M - 1), r1c = min(r1, M - 1);
  const ushort* a0p = A + (size_t)r0c * 256 + kg * 8;
  const ushort* a1p = A + (size_t)r1c * 256 + kg * 8;
  bf16x8 a0[8], a1[8];
#pragma unroll
  for (int kk = 0; kk < 8; ++kk) a0[kk] = *(const bf16x8*)(a0p + kk * 32);
#pragma unroll
  for (int kk = 0; kk < 8; ++kk) a1[kk] = *(const bf16x8*)(a1p + kk * 32);

  // ---- B panel fill: linear LDS dest, inverse-swizzled global source ----
  const ushort* wp = Wpan + (size_t)by * 128 * 256;
#pragma unroll
  for (int rnd = 0; rnd < 16; ++rnd) {
    int gi = rnd * 256 + tid;          // linear LDS granule (16 B) index 0..4095
    int col = gi >> 5;                 // 32 granules per col
    int gphys = gi & 31;
    int glog = gphys ^ (col & 7);      // involution
    __builtin_amdgcn_global_load_lds(
        (const __attribute__((address_space(1))) void*)(wp + (size_t)col * 256 + glog * 8),
        (__attribute__((address_space(3))) void*)(Bs + (size_t)(rnd * 256 + w * 64) * 8),
        16, 0, 0);
  }

  // bias prefetch (no LDS dependency)
  float bj[8];
#pragma unroll
  for (int ct = 0; ct < 8; ++ct) {
    int colg = by * 128 + ct * 16 + l15;
    if (MODE == 3) bj[ct] = (colg < 256) ? bias[colg] : bias2[colg - 256];
    else           bj[ct] = bias[colg];
  }

  __syncthreads();

  // ---- compute: both slices share each B-fragment read ----
  f32x4 acc0[8], acc1[8];
#pragma unroll
  for (int ct = 0; ct < 8; ++ct) {
    acc0[ct] = (f32x4){0.f, 0.f, 0.f, 0.f};
    acc1[ct] = (f32x4){0.f, 0.f, 0.f, 0.f};
  }
#pragma unroll
  for (int ct = 0; ct < 8; ++ct) {
    const int cb = (ct * 16 + l15) * 256;
#pragma unroll
    for (int kk = 0; kk < 8; ++kk) {
      bf16x8 b = *(const bf16x8*)(Bs + cb + (((kk * 4 + kg) ^ cxor) * 8));
      acc0[ct] = __builtin_amdgcn_mfma_f32_16x16x32_bf16(a0[kk], b, acc0[ct], 0, 0, 0);
      acc1[ct] = __builtin_amdgcn_mfma_f32_16x16x32_bf16(a1[kk], b, acc1[ct], 0, 0, 0);
    }
  }

  // ---- epilogue: D mapping col = lane&15, row = (lane>>4)*4 + r ----
  const int orow0 = bx * 128 + w * 16 + kg * 4;
#pragma unroll
  for (int sl = 0; sl < 2; ++sl) {
    const int rowb = orow0 + sl * 64;
#pragma unroll
    for (int ct = 0; ct < 8; ++ct) {
      const int colg = by * 128 + ct * 16 + l15;
#pragma unroll
      for (int r = 0; r < 4; ++r) {
        const int row = rowb + r;
        if (row >= M) continue;
        float v = (sl ? acc1[ct][r] : acc0[ct][r]) + bj[ct];
        if (MODE == 2) v = fmaxf(v, 0.f);
        if (MODE == 3) {
          if (colg < 256) ((float*)C )[(size_t)row * 256 + colg]       = v;
          else            ((float*)C2)[(size_t)row * 128 + (colg-256)] = v;
        } else if (MODE == 0) {
          ((float*)C)[(size_t)row * Ns + colg] = v;
        } else {
          ((ushort*)C)[(size_t)row * Ns + colg] = f2bf(v);
        }
      }
    }
  }
}

// ---------------- streaming bf16 MFMA GEMM (kept for FFN2, K=1024) ----------------
template<bool RELU, bool OUTBF16>
__global__ __launch_bounds__(256, 2)
void gemm_mfma(const ushort* __restrict__ A, const ushort* __restrict__ Wt,
               const float* __restrict__ bias, void* __restrict__ Cout,
               int M, int N, int K) {
  __shared__ ushort As[128 * 32];
  __shared__ ushort Bs[128 * 32];
  const int tid = threadIdx.x;
  const int l = tid & 63, w = tid >> 6;
  const int brow = blockIdx.x * 128, bcol = blockIdx.y * 128;

  const int rA0 = w * 32 + (l >> 2);
  const int kbl = (l & 3) ^ ((rA0 >> 1) & 3);
  const ushort* agp0 = A  + (size_t)(brow + rA0)      * K + kbl * 8;
  const ushort* agp1 = A  + (size_t)(brow + rA0 + 16) * K + kbl * 8;
  const ushort* bgp0 = Wt + (size_t)(bcol + rA0)      * K + kbl * 8;
  const ushort* bgp1 = Wt + (size_t)(bcol + rA0 + 16) * K + kbl * 8;
  ushort* asl0 = As + w * 1024; ushort* asl1 = asl0 + 512;
  ushort* bsl0 = Bs + w * 1024; ushort* bsl1 = bsl0 + 512;

  const int l15 = l & 15;
  const int kg  = l >> 4;
  const int swz = (l15 >> 1) & 3;
  const int rbase = (w & 1) * 64, cbase = (w >> 1) * 64;
  const int aoff = (rbase + l15) * 32 + ((kg ^ swz) * 8);
  const int boff = (cbase + l15) * 32 + ((kg ^ swz) * 8);

  f32x4 acc[4][4];
#pragma unroll
  for (int i = 0; i < 4; ++i)
#pragma unroll
    for (int j = 0; j < 4; ++j) acc[i][j] = (f32x4){0.f, 0.f, 0.f, 0.f};

  for (int bk = 0; bk < K; bk += 32) {
    __builtin_amdgcn_global_load_lds(
        (const __attribute__((address_space(1))) void*)(agp0 + bk),
        (__attribute__((address_space(3))) void*)asl0, 16, 0, 0);
    __builtin_amdgcn_global_load_lds(
        (const __attribute__((address_space(1))) void*)(agp1 + bk),
        (__attribute__((address_space(3))) void*)asl1, 16, 0, 0);
    __builtin_amdgcn_global_load_lds(
        (const __attribute__((address_space(1))) void*)(bgp0 + bk),
        (__attribute__((address_space(3))) void*)bsl0, 16, 0, 0);
    __builtin_amdgcn_global_load_lds(
        (const __attribute__((address_space(1))) void*)(bgp1 + bk),
        (__attribute__((address_space(3))) void*)bsl1, 16, 0, 0);
    __syncthreads();

    bf16x8 af[4], bfr[4];
#pragma unroll
    for (int i = 0; i < 4; ++i) af[i]  = *(const bf16x8*)(As + aoff + i * 512);
#pragma unroll
    for (int j = 0; j < 4; ++j) bfr[j] = *(const bf16x8*)(Bs + boff + j * 512);
#pragma unroll
    for (int i = 0; i < 4; ++i)
#pragma unroll
      for (int j = 0; j < 4; ++j)
        acc[i][j] = __builtin_amdgcn_mfma_f32_16x16x32_bf16(af[i], bfr[j], acc[i][j], 0, 0, 0);
    __syncthreads();
  }

  const int r0 = kg * 4;
#pragma unroll
  for (int j = 0; j < 4; ++j) {
    const int col = bcol + cbase + j * 16 + l15;
    const float bj = bias[col];
#pragma unroll
    for (int i = 0; i < 4; ++i) {
      const int rowb = brow + rbase + i * 16 + r0;
#pragma unroll
      for (int r = 0; r < 4; ++r) {
        const int row = rowb + r;
        if (row < M) {
          float v = acc[i][j][r] + bj;
          if (RELU) v = fmaxf(v, 0.f);
          if (OUTBF16) ((ushort*)Cout)[(size_t)row * N + col] = f2bf(v);
          else         ((float*)Cout)[(size_t)row * N + col]  = v;
        }
      }
    }
  }
}

// ---------------- MSDA sampling, descriptor-split + XCD-bijective swizzle ----------
__global__ __launch_bounds__(256)
void msda_kernel(const ushort* __restrict__ value, const float* __restrict__ offs,
                 const float* __restrict__ attn, const float* __restrict__ ref,
                 ushort* __restrict__ out) {
  __shared__ int4   descI[4 * 136];
  __shared__ float4 descW[4 * 136];
  const int t = threadIdx.x;
  // bijective XCD swizzle: nwg = 8330 = 8*1041 + 2 (m204 form)
  const int orig = blockIdx.x;
  const int xcd = orig & 7, ii = orig >> 3;
  const int wg = (xcd < 2 ? xcd * 1042 : 2 * 1042 + (xcd - 2) * 1041) + ii;
  const int n0 = wg * 4;

  const int Hs[4] = {112, 56, 28, 14};
  const int st[4] = {0, 12544, 15680, 16464};

  // ---- phase 1: 2 descriptors per thread ----
#pragma unroll
  for (int rep = 0; rep < 2; ++rep) {
    const int di = t + rep * 256;
    const int q = di >> 7, h = (di >> 4) & 7, lp = di & 15;
    const int lv = lp >> 2;
    const int n = n0 + q;

    float lg = attn[(size_t)n * 128 + h * 16 + lp];
    float mx = lg;
#pragma unroll
    for (int o = 8; o; o >>= 1) mx = fmaxf(mx, __shfl_xor(mx, o, 64));
    float e = __expf(lg - mx);
    float ssum = e;
#pragma unroll
    for (int o = 8; o; o >>= 1) ssum += __shfl_xor(ssum, o, 64);
    const float aw = e / ssum;

    const int Hl = Hs[lv], Wl = Hs[lv];
    const float fS = (float)Wl;
    const float refx = ref[((size_t)n * 4 + lv) * 2 + 0];
    const float refy = ref[((size_t)n * 4 + lv) * 2 + 1];
    const float ox = offs[(size_t)n * 256 + h * 32 + lp * 2 + 0];
    const float oy = offs[(size_t)n * 256 + h * 32 + lp * 2 + 1];
    float x = fmaf(refx, fS, ox) - 0.5f;
    float y = fmaf(refy, fS, oy) - 0.5f;
    float x0f = floorf(x), y0f = floorf(y);
    float dx = x - x0f, dy = y - y0f;
    int x0 = (int)x0f, y0 = (int)y0f;
    int x0c = min(max(x0, 0), Wl - 1), x1c = min(max(x0 + 1, 0), Wl - 1);
    int y0c = min(max(y0, 0), Hl - 1), y1c = min(max(y0 + 1, 0), Hl - 1);
    bool vx0 = (x0 >= 0) && (x0 < Wl), vx1 = (x0 + 1 >= 0) && (x0 + 1 < Wl);
    bool vy0 = (y0 >= 0) && (y0 < Hl), vy1 = (y0 + 1 >= 0) && (y0 + 1 < Hl);
    int4 I;
    I.x = st[lv] + y0c * Wl + x0c;
    I.y = st[lv] + y0c * Wl + x1c;
    I.z = st[lv] + y1c * Wl + x0c;
    I.w = st[lv] + y1c * Wl + x1c;
    float4 Wv;
    Wv.x = (1.f - dx) * (1.f - dy) * ((vx0 && vy0) ? aw : 0.f);
    Wv.y = dx * (1.f - dy)         * ((vx1 && vy0) ? aw : 0.f);
    Wv.z = (1.f - dx) * dy         * ((vx0 && vy1) ? aw : 0.f);
    Wv.w = dx * dy                 * ((vx1 && vy1) ? aw : 0.f);
    const int slot = q * 136 + h * 17 + lp;
    descI[slot] = I;
    descW[slot] = Wv;
  }
  __syncthreads();

  // ---- phase 2: wave per query, 8 lanes per head, 4 channels per lane ----
  const int q = t >> 6, lane = t & 63;
  const int h = lane >> 3, c = lane & 7;
  const int n = n0 + q;
  const int b = n / S_;
  const ushort* base = value + (size_t)b * S_ * 256 + h * 32 + c * 4;

  float a0 = 0.f, a1 = 0.f, a2 = 0.f, a3 = 0.f;
#pragma unroll
  for (int pt = 0; pt < 16; ++pt) {
    const int slot = q * 136 + h * 17 + pt;
    int4 I = descI[slot];
    float4 Wv = descW[slot];
    int   Ia[4] = {I.x, I.y, I.z, I.w};
    float Wa[4] = {Wv.x, Wv.y, Wv.z, Wv.w};
#pragma unroll
    for (int cr = 0; cr < 4; ++cr) {
      uint2 u = *(const uint2*)(base + (size_t)Ia[cr] * 256);
      float f0 = __uint_as_float(u.x << 16);
      float f1 = __uint_as_float(u.x & 0xffff0000u);
      float f2 = __uint_as_float(u.y << 16);
      float f3 = __uint_as_float(u.y & 0xffff0000u);
      a0 = fmaf(Wa[cr], f0, a0);
      a1 = fmaf(Wa[cr], f1, a1);
      a2 = fmaf(Wa[cr], f2, a2);
      a3 = fmaf(Wa[cr], f3, a3);
    }
  }
  ushort4 o = {f2bf(a0), f2bf(a1), f2bf(a2), f2bf(a3)};
  *(ushort4*)(out + (size_t)n * 256 + h * 32 + c * 4) = o;
}

// ---------------- residual add + LayerNorm (wave per row) ----------------
template<bool WB>
__global__ __launch_bounds__(256)
void add_ln_kernel(const float* __restrict__ a, const float* __restrict__ r,
                   const float* __restrict__ g, const float* __restrict__ be,
                   float* __restrict__ out, ushort* __restrict__ outb, int M) {
  const int wave = threadIdx.x >> 6;
  const int lane = threadIdx.x & 63;
  const int row = blockIdx.x * 4 + wave;
  if (row >= M) return;
  const float4 av = *(const float4*)(a + (size_t)row * 256 + lane * 4);
  const float4 rv = *(const float4*)(r + (size_t)row * 256 + lane * 4);
  float4 v = {av.x + rv.x, av.y + rv.y, av.z + rv.z, av.w + rv.w};
  float s  = v.x + v.y + v.z + v.w;
  float s2 = v.x * v.x + v.y * v.y + v.z * v.z + v.w * v.w;
#pragma unroll
  for (int o = 32; o > 0; o >>= 1) {
    s  += __shfl_xor(s, o, 64);
    s2 += __shfl_xor(s2, o, 64);
  }
  const float mean = s * (1.f / 256.f);
  const float var  = s2 * (1.f / 256.f) - mean * mean;
  const float rstd = rsqrtf(var + 1e-5f);
  const float4 gv = *(const float4*)(g + lane * 4);
  const float4 bv = *(const float4*)(be + lane * 4);
  float4 o4;
  o4.x = (v.x - mean) * rstd * gv.x + bv.x;
  o4.y = (v.y - mean) * rstd * gv.y + bv.y;
  o4.z = (v.z - mean) * rstd * gv.z + bv.z;
  o4.w = (v.w - mean) * rstd * gv.w + bv.w;
  *(float4*)(out + (size_t)row * 256 + lane * 4) = o4;
  if (WB) {
    ushort4 ob = {f2bf(o4.x), f2bf(o4.y), f2bf(o4.z), f2bf(o4.w)};
    ((ushort4*)(outb + (size_t)row * 256))[lane] = ob;
  }
}

// ---------------- launch ----------------
extern "C" void kernel_launch(void* const* d_in, const int* in_sizes, int n_in,
                              void* d_out, int out_size, void* d_ws, size_t ws_size,
                              hipStream_t stream) {
  const float* src    = (const float*)d_in[0];
  const float* pos    = (const float*)d_in[1];
  const float* refpts = (const float*)d_in[2];
  const float* W_off  = (const float*)d_in[5];
  const float* b_off  = (const float*)d_in[6];
  const float* W_attn = (const float*)d_in[7];
  const float* b_attn = (const float*)d_in[8];
  const float* W_val  = (const float*)d_in[9];
  const float* b_val  = (const float*)d_in[10];
  const float* W_out  = (const float*)d_in[11];
  const float* b_out  = (const float*)d_in[12];
  const float* g1     = (const float*)d_in[13];
  const float* be1    = (const float*)d_in[14];
  const float* g2     = (const float*)d_in[15];
  const float* be2    = (const float*)d_in[16];
  const float* W1     = (const float*)d_in[17];
  const float* b1     = (const float*)d_in[18];
  const float* W2     = (const float*)d_in[19];
  const float* b2     = (const float*)d_in[20];
  float* out = (float*)d_out;

  const size_t NF = (size_t)NR_ * 256;
  char* p = (char*)d_ws;
  ushort* qb   = (ushort*)p; p += NF * 2;   // xb overlays qb
  ushort* srcb = (ushort*)p; p += NF * 2;   // msdab overlays srcb
  ushort* valb = (ushort*)p; p += NF * 2;   // hid overlays valb..attn
  float*  offs = (float*) p; p += NF * 4;
  float*  attn = (float*) p; p += NF * 2;   // [N,128] fp32
  float*  tmp  = (float*) p; p += NF * 4;
  float*  x    = (float*) p; p += NF * 4;
  ushort* Wt   = (ushort*)p; p += 753664 * 2;
  ushort* msdab = srcb;
  ushort* xb    = qb;
  ushort* hid   = valb;
  ushort* WtVal = Wt;
  ushort* WtOA  = Wt + 65536;    // [384,256]: off cols then attn cols
  ushort* WtOut = Wt + 163840;
  ushort* Wt1   = Wt + 229376;
  ushort* Wt2   = Wt + 491520;

  dim3 blk(256);
  const int n4 = NR_ * 64;
  const int gr = (NR_ + 127) / 128;   // 261

  prep_kernel<<<(n4 + 255) / 256, blk, 0, stream>>>(src, pos, qb, srcb, n4);
  cvt_weights<<<dim3(1024, 6), blk, 0, stream>>>(W_off, W_attn, W_val, W_out, W1, W2, Wt);
  // value = src @ W_val + b_val (bf16 out)
  gemm_blds<1><<<dim3(gr, 2), blk, 0, stream>>>(srcb, WtVal, b_val, nullptr,
                                                valb, nullptr, NR_, 256);
  // offsets + attn logits, merged N=384 GEMM with split epilogue
  gemm_blds<3><<<dim3(gr, 3), blk, 0, stream>>>(qb, WtOA, b_off, b_attn,
                                                offs, attn, NR_, 0);
  // sampling
  msda_kernel<<<NR_ / 4, blk, 0, stream>>>(valb, offs, attn, refpts, msdab);
  // out-proj (fp32 out)
  gemm_blds<0><<<dim3(gr, 2), blk, 0, stream>>>(msdab, WtOut, b_out, nullptr,
                                                tmp, nullptr, NR_, 256);
  // x = LN(src + tmp), bf16 copy for FFN
  add_ln_kernel<true ><<<(NR_ + 3) / 4, blk, 0, stream>>>(tmp, src, g1, be1, x, xb, NR_);
  // FFN1: hid = relu(x @ W1 + b1), bf16 out
  gemm_blds<2><<<dim3(gr, 8), blk, 0, stream>>>(xb, Wt1, b1, nullptr,
                                                hid, nullptr, NR_, 1024);
  // FFN2: K=1024 streaming GEMM (fp32 out)
  gemm_mfma<false, false><<<dim3(gr, 2), blk, 0, stream>>>(hid, Wt2, b2, tmp, NR_, 256, 1024);
  // out = LN(x + tmp)
  add_ln_kernel<false><<<(NR_ + 3) / 4, blk, 0, stream>>>(tmp, x, g2, be2, out, nullptr, NR_);
}

// Round 9
// 396.733 us; speedup vs baseline: 2.9266x; 1.0350x over previous
//
#include <hip/hip_runtime.h>

// ---------------- problem constants ----------------
constexpr int D_   = 256;
constexpr int NH_  = 8;
constexpr int DH_  = 32;
constexpr int NL_  = 4;
constexpr int NP_  = 4;
constexpr int FF_  = 1024;
constexpr int B_   = 2;
constexpr int S_   = 16660;
constexpr int NR_  = B_ * S_;   // 33320 rows

typedef __attribute__((ext_vector_type(8))) short bf16x8;
typedef __attribute__((ext_vector_type(4))) float f32x4;

__device__ __forceinline__ ushort f2bf(float f) {
  unsigned u = __float_as_uint(f);
  return (ushort)((u + 0x7FFFu + ((u >> 16) & 1u)) >> 16);
}

// ---------------- prep: qb = bf16(src+pos), srcb = bf16(src) ----------------
__global__ __launch_bounds__(256)
void prep_kernel(const float* __restrict__ src, const float* __restrict__ pos,
                 ushort* __restrict__ qb, ushort* __restrict__ srcb, int n4) {
  int i = blockIdx.x * 256 + threadIdx.x;
  if (i >= n4) return;
  float4 s = ((const float4*)src)[i];
  float4 p = ((const float4*)pos)[i];
  ushort4 sb = {f2bf(s.x), f2bf(s.y), f2bf(s.z), f2bf(s.w)};
  ushort4 q  = {f2bf(s.x + p.x), f2bf(s.y + p.y), f2bf(s.z + p.z), f2bf(s.w + p.w)};
  ((ushort4*)srcb)[i] = sb;
  ((ushort4*)qb)[i]   = q;
}

// ---------------- weight convert + transpose: Wt[n][k] = bf16(W[k][n]) ----------------
// layout (ushort offsets): Val 0 | OA(off 256 cols + attn 128 cols) 65536 | Out 163840
//                          | W1 229376 | W2 491520  (total 753664)
__global__ __launch_bounds__(256)
void cvt_weights(const float* __restrict__ Woff, const float* __restrict__ Wattn,
                 const float* __restrict__ Wval, const float* __restrict__ Wout,
                 const float* __restrict__ W1,  const float* __restrict__ W2,
                 ushort* __restrict__ out) {
  const int wi = blockIdx.y;
  const int i = blockIdx.x * 256 + threadIdx.x;
  const float* src; int K, N; size_t off;
  switch (wi) {
    case 0: src = Wval;  K = 256;  N = 256;  off = 0;      break;
    case 1: src = Woff;  K = 256;  N = 256;  off = 65536;  break;
    case 2: src = Wattn; K = 256;  N = 128;  off = 131072; break;
    case 3: src = Wout;  K = 256;  N = 256;  off = 163840; break;
    case 4: src = W1;    K = 256;  N = 1024; off = 229376; break;
    default:src = W2;    K = 1024; N = 256;  off = 491520; break;
  }
  if (i >= K * N) return;
  int k = i / N, n = i - k * N;
  out[off + (size_t)n * K + k] = f2bf(src[i]);
}

// ---------------- B-in-LDS GEMM for K=256: C[M,N] = A[M,256] @ Wpan^T + bias --------
// MODE: 0 = f32 out, 1 = bf16 out, 2 = bf16+relu out, 3 = split offs(f32)/attn(f32)
template<int MODE>
__global__ __launch_bounds__(256, 2)
void gemm_blds(const ushort* __restrict__ A, const ushort* __restrict__ Wpan,
               const float* __restrict__ bias, const float* __restrict__ bias2,
               void* __restrict__ C, void* __restrict__ C2, int M, int Ns) {
  __shared__ ushort Bs[128 * 256];   // 64 KB, [col][k] with k-granule XOR swizzle
  const int tid = threadIdx.x;
  const int l = tid & 63, w = tid >> 6;
  const int l15 = l & 15, kg = l >> 4;
  const int cxor = l15 & 7;
  const int bx = blockIdx.x, by = blockIdx.y;

  const int r0 = bx * 128 + w * 16 + l15;
  const int r1 = r0 + 64;
  const int r0c = min(r0, M - 1), r1c = min(r1, M - 1);
  const ushort* a0p = A + (size_t)r0c * 256 + kg * 8;
  const ushort* a1p = A + (size_t)r1c * 256 + kg * 8;
  bf16x8 a0[8], a1[8];
#pragma unroll
  for (int kk = 0; kk < 8; ++kk) a0[kk] = *(const bf16x8*)(a0p + kk * 32);
#pragma unroll
  for (int kk = 0; kk < 8; ++kk) a1[kk] = *(const bf16x8*)(a1p + kk * 32);

  const ushort* wp = Wpan + (size_t)by * 128 * 256;
#pragma unroll
  for (int rnd = 0; rnd < 16; ++rnd) {
    int gi = rnd * 256 + tid;
    int col = gi >> 5;
    int gphys = gi & 31;
    int glog = gphys ^ (col & 7);
    __builtin_amdgcn_global_load_lds(
        (const __attribute__((address_space(1))) void*)(wp + (size_t)col * 256 + glog * 8),
        (__attribute__((address_space(3))) void*)(Bs + (size_t)(rnd * 256 + w * 64) * 8),
        16, 0, 0);
  }

  float bj[8];
#pragma unroll
  for (int ct = 0; ct < 8; ++ct) {
    int colg = by * 128 + ct * 16 + l15;
    if (MODE == 3) bj[ct] = (colg < 256) ? bias[colg] : bias2[colg - 256];
    else           bj[ct] = bias[colg];
  }

  __syncthreads();

  f32x4 acc0[8], acc1[8];
#pragma unroll
  for (int ct = 0; ct < 8; ++ct) {
    acc0[ct] = (f32x4){0.f, 0.f, 0.f, 0.f};
    acc1[ct] = (f32x4){0.f, 0.f, 0.f, 0.f};
  }
#pragma unroll
  for (int ct = 0; ct < 8; ++ct) {
    const int cb = (ct * 16 + l15) * 256;
#pragma unroll
    for (int kk = 0; kk < 8; ++kk) {
      bf16x8 b = *(const bf16x8*)(Bs + cb + (((kk * 4 + kg) ^ cxor) * 8));
      acc0[ct] = __builtin_amdgcn_mfma_f32_16x16x32_bf16(a0[kk], b, acc0[ct], 0, 0, 0);
      acc1[ct] = __builtin_amdgcn_mfma_f32_16x16x32_bf16(a1[kk], b, acc1[ct], 0, 0, 0);
    }
  }

  const int orow0 = bx * 128 + w * 16 + kg * 4;
#pragma unroll
  for (int sl = 0; sl < 2; ++sl) {
    const int rowb = orow0 + sl * 64;
#pragma unroll
    for (int ct = 0; ct < 8; ++ct) {
      const int colg = by * 128 + ct * 16 + l15;
#pragma unroll
      for (int r = 0; r < 4; ++r) {
        const int row = rowb + r;
        if (row >= M) continue;
        float v = (sl ? acc1[ct][r] : acc0[ct][r]) + bj[ct];
        if (MODE == 2) v = fmaxf(v, 0.f);
        if (MODE == 3) {
          if (colg < 256) ((float*)C )[(size_t)row * 256 + colg]       = v;
          else            ((float*)C2)[(size_t)row * 128 + (colg-256)] = v;
        } else if (MODE == 0) {
          ((float*)C)[(size_t)row * Ns + colg] = v;
        } else {
          ((ushort*)C)[(size_t)row * Ns + colg] = f2bf(v);
        }
      }
    }
  }
}

// ---------------- B-in-LDS GEMM for K=1024 (FFN2): 4 chunks of 256 K ----------------
// Same fragment/swizzle math as gemm_blds; weight sub-panel 64 KB LDS-resident per
// chunk; 2 barriers per chunk (8 total vs streaming's 64). fp32 out.
__global__ __launch_bounds__(256, 2)
void gemm_blds1024(const ushort* __restrict__ A, const ushort* __restrict__ Wpan,
                   const float* __restrict__ bias, float* __restrict__ C, int M) {
  __shared__ ushort Bs[128 * 256];   // 64 KB
  const int tid = threadIdx.x;
  const int l = tid & 63, w = tid >> 6;
  const int l15 = l & 15, kg = l >> 4;
  const int cxor = l15 & 7;
  const int bx = blockIdx.x, by = blockIdx.y;

  const int r0 = bx * 128 + w * 16 + l15;
  const int r1 = r0 + 64;
  const int r0c = min(r0, M - 1), r1c = min(r1, M - 1);
  const ushort* a0p = A + (size_t)r0c * 1024 + kg * 8;
  const ushort* a1p = A + (size_t)r1c * 1024 + kg * 8;
  const ushort* wp = Wpan + (size_t)by * 128 * 1024;

  float bj[8];
#pragma unroll
  for (int ct = 0; ct < 8; ++ct) bj[ct] = bias[by * 128 + ct * 16 + l15];

  f32x4 acc0[8], acc1[8];
#pragma unroll
  for (int ct = 0; ct < 8; ++ct) {
    acc0[ct] = (f32x4){0.f, 0.f, 0.f, 0.f};
    acc1[ct] = (f32x4){0.f, 0.f, 0.f, 0.f};
  }

  for (int kc = 0; kc < 4; ++kc) {
    // stage chunk kc (prev compute finished at loop-end barrier)
#pragma unroll
    for (int rnd = 0; rnd < 16; ++rnd) {
      int gi = rnd * 256 + tid;
      int col = gi >> 5;
      int gphys = gi & 31;
      int glog = gphys ^ (col & 7);
      __builtin_amdgcn_global_load_lds(
          (const __attribute__((address_space(1))) void*)
              (wp + (size_t)col * 1024 + kc * 256 + glog * 8),
          (__attribute__((address_space(3))) void*)(Bs + (size_t)(rnd * 256 + w * 64) * 8),
          16, 0, 0);
    }
    // A fragments for this chunk (overlap with staging)
    bf16x8 a0[8], a1[8];
#pragma unroll
    for (int kk = 0; kk < 8; ++kk) a0[kk] = *(const bf16x8*)(a0p + kc * 256 + kk * 32);
#pragma unroll
    for (int kk = 0; kk < 8; ++kk) a1[kk] = *(const bf16x8*)(a1p + kc * 256 + kk * 32);

    __syncthreads();   // vmcnt(0) drain: staging + A-loads complete

#pragma unroll
    for (int ct = 0; ct < 8; ++ct) {
      const int cb = (ct * 16 + l15) * 256;
#pragma unroll
      for (int kk = 0; kk < 8; ++kk) {
        bf16x8 b = *(const bf16x8*)(Bs + cb + (((kk * 4 + kg) ^ cxor) * 8));
        acc0[ct] = __builtin_amdgcn_mfma_f32_16x16x32_bf16(a0[kk], b, acc0[ct], 0, 0, 0);
        acc1[ct] = __builtin_amdgcn_mfma_f32_16x16x32_bf16(a1[kk], b, acc1[ct], 0, 0, 0);
      }
    }
    __syncthreads();   // all waves done reading Bs before next-stage overwrite
  }

  const int orow0 = bx * 128 + w * 16 + kg * 4;
#pragma unroll
  for (int sl = 0; sl < 2; ++sl) {
    const int rowb = orow0 + sl * 64;
#pragma unroll
    for (int ct = 0; ct < 8; ++ct) {
      const int colg = by * 128 + ct * 16 + l15;
#pragma unroll
      for (int r = 0; r < 4; ++r) {
        const int row = rowb + r;
        if (row >= M) continue;
        C[(size_t)row * 256 + colg] = (sl ? acc1[ct][r] : acc0[ct][r]) + bj[ct];
      }
    }
  }
}

// ---------------- streaming bf16 MFMA GEMM (unused fallback, uninstantiated) --------
template<bool RELU, bool OUTBF16>
__global__ __launch_bounds__(256, 2)
void gemm_mfma(const ushort* __restrict__ A, const ushort* __restrict__ Wt,
               const float* __restrict__ bias, void* __restrict__ Cout,
               int M, int N, int K) {
  __shared__ ushort As[128 * 32];
  __shared__ ushort Bs[128 * 32];
  const int tid = threadIdx.x;
  const int l = tid & 63, w = tid >> 6;
  const int brow = blockIdx.x * 128, bcol = blockIdx.y * 128;
  const int rA0 = w * 32 + (l >> 2);
  const int kbl = (l & 3) ^ ((rA0 >> 1) & 3);
  const ushort* agp0 = A  + (size_t)(brow + rA0)      * K + kbl * 8;
  const ushort* agp1 = A  + (size_t)(brow + rA0 + 16) * K + kbl * 8;
  const ushort* bgp0 = Wt + (size_t)(bcol + rA0)      * K + kbl * 8;
  const ushort* bgp1 = Wt + (size_t)(bcol + rA0 + 16) * K + kbl * 8;
  ushort* asl0 = As + w * 1024; ushort* asl1 = asl0 + 512;
  ushort* bsl0 = Bs + w * 1024; ushort* bsl1 = bsl0 + 512;
  const int l15 = l & 15;
  const int kg  = l >> 4;
  const int swz = (l15 >> 1) & 3;
  const int rbase = (w & 1) * 64, cbase = (w >> 1) * 64;
  const int aoff = (rbase + l15) * 32 + ((kg ^ swz) * 8);
  const int boff = (cbase + l15) * 32 + ((kg ^ swz) * 8);
  f32x4 acc[4][4];
#pragma unroll
  for (int i = 0; i < 4; ++i)
#pragma unroll
    for (int j = 0; j < 4; ++j) acc[i][j] = (f32x4){0.f, 0.f, 0.f, 0.f};
  for (int bk = 0; bk < K; bk += 32) {
    __builtin_amdgcn_global_load_lds(
        (const __attribute__((address_space(1))) void*)(agp0 + bk),
        (__attribute__((address_space(3))) void*)asl0, 16, 0, 0);
    __builtin_amdgcn_global_load_lds(
        (const __attribute__((address_space(1))) void*)(agp1 + bk),
        (__attribute__((address_space(3))) void*)asl1, 16, 0, 0);
    __builtin_amdgcn_global_load_lds(
        (const __attribute__((address_space(1))) void*)(bgp0 + bk),
        (__attribute__((address_space(3))) void*)bsl0, 16, 0, 0);
    __builtin_amdgcn_global_load_lds(
        (const __attribute__((address_space(1))) void*)(bgp1 + bk),
        (__attribute__((address_space(3))) void*)bsl1, 16, 0, 0);
    __syncthreads();
    bf16x8 af[4], bfr[4];
#pragma unroll
    for (int i = 0; i < 4; ++i) af[i]  = *(const bf16x8*)(As + aoff + i * 512);
#pragma unroll
    for (int j = 0; j < 4; ++j) bfr[j] = *(const bf16x8*)(Bs + boff + j * 512);
#pragma unroll
    for (int i = 0; i < 4; ++i)
#pragma unroll
      for (int j = 0; j < 4; ++j)
        acc[i][j] = __builtin_amdgcn_mfma_f32_16x16x32_bf16(af[i], bfr[j], acc[i][j], 0, 0, 0);
    __syncthreads();
  }
  const int r0 = kg * 4;
#pragma unroll
  for (int j = 0; j < 4; ++j) {
    const int col = bcol + cbase + j * 16 + l15;
    const float bj = bias[col];
#pragma unroll
    for (int i = 0; i < 4; ++i) {
      const int rowb = brow + rbase + i * 16 + r0;
#pragma unroll
      for (int r = 0; r < 4; ++r) {
        const int row = rowb + r;
        if (row < M) {
          float v = acc[i][j][r] + bj;
          if (RELU) v = fmaxf(v, 0.f);
          if (OUTBF16) ((ushort*)Cout)[(size_t)row * N + col] = f2bf(v);
          else         ((float*)Cout)[(size_t)row * N + col]  = v;
        }
      }
    }
  }
}

// ---------------- MSDA sampling: descriptor split + wide (16 B) gathers -------------
// Phase 1 unchanged: 512 descriptors to LDS. Phase 2: wave per query; lane owns 16 B
// (8 channels) of one head; wave halves process even/odd points; shfl_xor(32) combine.
__global__ __launch_bounds__(256)
void msda_kernel(const ushort* __restrict__ value, const float* __restrict__ offs,
                 const float* __restrict__ attn, const float* __restrict__ ref,
                 ushort* __restrict__ out) {
  __shared__ int4   descI[4 * 136];
  __shared__ float4 descW[4 * 136];
  const int t = threadIdx.x;
  // bijective XCD swizzle: nwg = 8330 = 8*1041 + 2 (m204 form)
  const int orig = blockIdx.x;
  const int xcd = orig & 7, ii = orig >> 3;
  const int wg = (xcd < 2 ? xcd * 1042 : 2 * 1042 + (xcd - 2) * 1041) + ii;
  const int n0 = wg * 4;

  const int Hs[4] = {112, 56, 28, 14};
  const int st[4] = {0, 12544, 15680, 16464};

  // ---- phase 1: 2 descriptors per thread ----
#pragma unroll
  for (int rep = 0; rep < 2; ++rep) {
    const int di = t + rep * 256;
    const int q = di >> 7, h = (di >> 4) & 7, lp = di & 15;
    const int lv = lp >> 2;
    const int n = n0 + q;

    float lg = attn[(size_t)n * 128 + h * 16 + lp];
    float mx = lg;
#pragma unroll
    for (int o = 8; o; o >>= 1) mx = fmaxf(mx, __shfl_xor(mx, o, 64));
    float e = __expf(lg - mx);
    float ssum = e;
#pragma unroll
    for (int o = 8; o; o >>= 1) ssum += __shfl_xor(ssum, o, 64);
    const float aw = e / ssum;

    const int Hl = Hs[lv], Wl = Hs[lv];
    const float fS = (float)Wl;
    const float refx = ref[((size_t)n * 4 + lv) * 2 + 0];
    const float refy = ref[((size_t)n * 4 + lv) * 2 + 1];
    const float ox = offs[(size_t)n * 256 + h * 32 + lp * 2 + 0];
    const float oy = offs[(size_t)n * 256 + h * 32 + lp * 2 + 1];
    float x = fmaf(refx, fS, ox) - 0.5f;
    float y = fmaf(refy, fS, oy) - 0.5f;
    float x0f = floorf(x), y0f = floorf(y);
    float dx = x - x0f, dy = y - y0f;
    int x0 = (int)x0f, y0 = (int)y0f;
    int x0c = min(max(x0, 0), Wl - 1), x1c = min(max(x0 + 1, 0), Wl - 1);
    int y0c = min(max(y0, 0), Hl - 1), y1c = min(max(y0 + 1, 0), Hl - 1);
    bool vx0 = (x0 >= 0) && (x0 < Wl), vx1 = (x0 + 1 >= 0) && (x0 + 1 < Wl);
    bool vy0 = (y0 >= 0) && (y0 < Hl), vy1 = (y0 + 1 >= 0) && (y0 + 1 < Hl);
    int4 I;
    I.x = st[lv] + y0c * Wl + x0c;
    I.y = st[lv] + y0c * Wl + x1c;
    I.z = st[lv] + y1c * Wl + x0c;
    I.w = st[lv] + y1c * Wl + x1c;
    float4 Wv;
    Wv.x = (1.f - dx) * (1.f - dy) * ((vx0 && vy0) ? aw : 0.f);
    Wv.y = dx * (1.f - dy)         * ((vx1 && vy0) ? aw : 0.f);
    Wv.z = (1.f - dx) * dy         * ((vx0 && vy1) ? aw : 0.f);
    Wv.w = dx * dy                 * ((vx1 && vy1) ? aw : 0.f);
    const int slot = q * 136 + h * 17 + lp;
    descI[slot] = I;
    descW[slot] = Wv;
  }
  __syncthreads();

  // ---- phase 2: lane = (pth, h, cq): 16 B of head h, even/odd points by pth ----
  const int q = t >> 6, lane = t & 63;
  const int pth = lane >> 5;          // 0: even points, 1: odd points
  const int h  = (lane >> 2) & 7;
  const int cq = lane & 3;            // which 16 B quarter of the 64 B head row
  const int n = n0 + q;
  const int b = n / S_;
  const ushort* base = value + (size_t)b * S_ * 256 + h * 32 + cq * 8;

  float a[8] = {0.f, 0.f, 0.f, 0.f, 0.f, 0.f, 0.f, 0.f};
#pragma unroll
  for (int pt2 = 0; pt2 < 8; ++pt2) {
    const int pt = pt2 * 2 + pth;
    const int slot = q * 136 + h * 17 + pt;
    int4 I = descI[slot];
    float4 Wv = descW[slot];
    int   Ia[4] = {I.x, I.y, I.z, I.w};
    float Wa[4] = {Wv.x, Wv.y, Wv.z, Wv.w};
#pragma unroll
    for (int cr = 0; cr < 4; ++cr) {
      uint4 u = *(const uint4*)(base + (size_t)Ia[cr] * 256);
      const float wgt = Wa[cr];
      a[0] = fmaf(wgt, __uint_as_float(u.x << 16),         a[0]);
      a[1] = fmaf(wgt, __uint_as_float(u.x & 0xffff0000u), a[1]);
      a[2] = fmaf(wgt, __uint_as_float(u.y << 16),         a[2]);
      a[3] = fmaf(wgt, __uint_as_float(u.y & 0xffff0000u), a[3]);
      a[4] = fmaf(wgt, __uint_as_float(u.z << 16),         a[4]);
      a[5] = fmaf(wgt, __uint_as_float(u.z & 0xffff0000u), a[5]);
      a[6] = fmaf(wgt, __uint_as_float(u.w << 16),         a[6]);
      a[7] = fmaf(wgt, __uint_as_float(u.w & 0xffff0000u), a[7]);
    }
  }
  // combine even/odd point halves
#pragma unroll
  for (int i = 0; i < 8; ++i) a[i] += __shfl_xor(a[i], 32, 64);
  if (pth == 0) {
    uint4 o;
    o.x = ((uint)f2bf(a[1]) << 16) | f2bf(a[0]);
    o.y = ((uint)f2bf(a[3]) << 16) | f2bf(a[2]);
    o.z = ((uint)f2bf(a[5]) << 16) | f2bf(a[4]);
    o.w = ((uint)f2bf(a[7]) << 16) | f2bf(a[6]);
    *(uint4*)(out + (size_t)n * 256 + h * 32 + cq * 8) = o;
  }
}

// ---------------- residual add + LayerNorm (wave per row) ----------------
template<bool WB>
__global__ __launch_bounds__(256)
void add_ln_kernel(const float* __restrict__ a, const float* __restrict__ r,
                   const float* __restrict__ g, const float* __restrict__ be,
                   float* __restrict__ out, ushort* __restrict__ outb, int M) {
  const int wave = threadIdx.x >> 6;
  const int lane = threadIdx.x & 63;
  const int row = blockIdx.x * 4 + wave;
  if (row >= M) return;
  const float4 av = *(const float4*)(a + (size_t)row * 256 + lane * 4);
  const float4 rv = *(const float4*)(r + (size_t)row * 256 + lane * 4);
  float4 v = {av.x + rv.x, av.y + rv.y, av.z + rv.z, av.w + rv.w};
  float s  = v.x + v.y + v.z + v.w;
  float s2 = v.x * v.x + v.y * v.y + v.z * v.z + v.w * v.w;
#pragma unroll
  for (int o = 32; o > 0; o >>= 1) {
    s  += __shfl_xor(s, o, 64);
    s2 += __shfl_xor(s2, o, 64);
  }
  const float mean = s * (1.f / 256.f);
  const float var  = s2 * (1.f / 256.f) - mean * mean;
  const float rstd = rsqrtf(var + 1e-5f);
  const float4 gv = *(const float4*)(g + lane * 4);
  const float4 bv = *(const float4*)(be + lane * 4);
  float4 o4;
  o4.x = (v.x - mean) * rstd * gv.x + bv.x;
  o4.y = (v.y - mean) * rstd * gv.y + bv.y;
  o4.z = (v.z - mean) * rstd * gv.z + bv.z;
  o4.w = (v.w - mean) * rstd * gv.w + bv.w;
  *(float4*)(out + (size_t)row * 256 + lane * 4) = o4;
  if (WB) {
    ushort4 ob = {f2bf(o4.x), f2bf(o4.y), f2bf(o4.z), f2bf(o4.w)};
    ((ushort4*)(outb + (size_t)row * 256))[lane] = ob;
  }
}

// ---------------- launch ----------------
extern "C" void kernel_launch(void* const* d_in, const int* in_sizes, int n_in,
                              void* d_out, int out_size, void* d_ws, size_t ws_size,
                              hipStream_t stream) {
  const float* src    = (const float*)d_in[0];
  const float* pos    = (const float*)d_in[1];
  const float* refpts = (const float*)d_in[2];
  const float* W_off  = (const float*)d_in[5];
  const float* b_off  = (const float*)d_in[6];
  const float* W_attn = (const float*)d_in[7];
  const float* b_attn = (const float*)d_in[8];
  const float* W_val  = (const float*)d_in[9];
  const float* b_val  = (const float*)d_in[10];
  const float* W_out  = (const float*)d_in[11];
  const float* b_out  = (const float*)d_in[12];
  const float* g1     = (const float*)d_in[13];
  const float* be1    = (const float*)d_in[14];
  const float* g2     = (const float*)d_in[15];
  const float* be2    = (const float*)d_in[16];
  const float* W1     = (const float*)d_in[17];
  const float* b1     = (const float*)d_in[18];
  const float* W2     = (const float*)d_in[19];
  const float* b2     = (const float*)d_in[20];
  float* out = (float*)d_out;

  const size_t NF = (size_t)NR_ * 256;
  char* p = (char*)d_ws;
  ushort* qb   = (ushort*)p; p += NF * 2;   // xb overlays qb
  ushort* srcb = (ushort*)p; p += NF * 2;   // msdab overlays srcb
  ushort* valb = (ushort*)p; p += NF * 2;   // hid overlays valb..attn
  float*  offs = (float*) p; p += NF * 4;
  float*  attn = (float*) p; p += NF * 2;   // [N,128] fp32
  float*  tmp  = (float*) p; p += NF * 4;
  float*  x    = (float*) p; p += NF * 4;
  ushort* Wt   = (ushort*)p; p += 753664 * 2;
  ushort* msdab = srcb;
  ushort* xb    = qb;
  ushort* hid   = valb;
  ushort* WtVal = Wt;
  ushort* WtOA  = Wt + 65536;    // [384,256]: off cols then attn cols
  ushort* WtOut = Wt + 163840;
  ushort* Wt1   = Wt + 229376;
  ushort* Wt2   = Wt + 491520;

  dim3 blk(256);
  const int n4 = NR_ * 64;
  const int gr = (NR_ + 127) / 128;   // 261

  prep_kernel<<<(n4 + 255) / 256, blk, 0, stream>>>(src, pos, qb, srcb, n4);
  cvt_weights<<<dim3(1024, 6), blk, 0, stream>>>(W_off, W_attn, W_val, W_out, W1, W2, Wt);
  // value = src @ W_val + b_val (bf16 out)
  gemm_blds<1><<<dim3(gr, 2), blk, 0, stream>>>(srcb, WtVal, b_val, nullptr,
                                                valb, nullptr, NR_, 256);
  // offsets + attn logits, merged N=384 GEMM with split epilogue
  gemm_blds<3><<<dim3(gr, 3), blk, 0, stream>>>(qb, WtOA, b_off, b_attn,
                                                offs, attn, NR_, 0);
  // sampling
  msda_kernel<<<NR_ / 4, blk, 0, stream>>>(valb, offs, attn, refpts, msdab);
  // out-proj (fp32 out)
  gemm_blds<0><<<dim3(gr, 2), blk, 0, stream>>>(msdab, WtOut, b_out, nullptr,
                                                tmp, nullptr, NR_, 256);
  // x = LN(src + tmp), bf16 copy for FFN
  add_ln_kernel<true ><<<(NR_ + 3) / 4, blk, 0, stream>>>(tmp, src, g1, be1, x, xb, NR_);
  // FFN1: hid = relu(x @ W1 + b1), bf16 out
  gemm_blds<2><<<dim3(gr, 8), blk, 0, stream>>>(xb, Wt1, b1, nullptr,
                                                hid, nullptr, NR_, 1024);
  // FFN2: K=1024 panel-resident GEMM (fp32 out)
  gemm_blds1024<<<dim3(gr, 2), blk, 0, stream>>>(hid, Wt2, b2, tmp, NR_);
  // out = LN(x + tmp)
  add_ln_kernel<false><<<(NR_ + 3) / 4, blk, 0, stream>>>(tmp, x, g2, be2, out, nullptr, NR_);
}